// Round 5
// baseline (294.174 us; speedup 1.0000x reference)
//
#include <hip/hip_runtime.h>
#include <cstdint>

#define S_FRAMES 64
#define NPF      147456           // 384*384
#define TOT      (S_FRAMES * NPF) // 9437184
#define NBINS    4096
#define R1       73728u           // valid = c >= sorted[R1]  (== c >= median, exactly)
#define NBLK_STATS 2048
#define CAP      512
#define WORDS_BM 9344             // 8192 (dim64,λ40) + 1024 (dim32,λ20) + 128 (dim16,λ10)

// ---- workspace layout (bytes) ----
#define OFF_SL   0                                  // hist slices: 512 * 4096 * 4 = 8 MB
#define SZ_SL    (S_FRAMES * 8 * NBINS * 4)
#define OFF_CTRS SZ_SL                              // 320 u32: done1[64] done2[64] done3[64] done4[64] ccnt[64]
#define OFF_HDR  (OFF_CTRS + 320 * 4)               // 64 * 2 u32 {bin1, cb1}
#define OFF_MED  (OFF_HDR + S_FRAMES * 8)           // 64 f32
#define OFF_BBOX (OFF_MED + 256)                    // 6 f32 (+pad)
#define OFF_SUMS (OFF_BBOX + 64)                    // 3 f64
#define OFF_CAND (OFF_SUMS + 64)                    // 64 * 512 f32
#define OFF_PBF  (OFF_CAND + S_FRAMES * CAP * 4)    // 2048*6 f32
#define OFF_PBD  (OFF_PBF + NBLK_STATS * 6 * 4)     // 2048*2 f64
#define OFF_PBC  (OFF_PBD + NBLK_STATS * 2 * 8)     // 2048 u32
#define OFF_VSL  (OFF_PBC + NBLK_STATS * 4)         // voxel slices: 512 * 9344 * 4 = 19.1 MB

__device__ __forceinline__ int conf_bin(float v) {
    int b = (int)(v * (float)NBINS);
    return b < 0 ? 0 : (b > NBINS - 1 ? NBINS - 1 : b);
}

// K0: zero the control counters (done1/done2/done3/done4/ccnt) — required each call
__global__ __launch_bounds__(256) void k_init(uint32_t* __restrict__ ctrs) {
    for (int i = threadIdx.x; i < 320; i += 256) ctrs[i] = 0u;
}

// K1: per-frame conf histogram, 8 blocks/frame, float4 loads; per-block slices.
// Last block of each frame sums the 8 slices and locates the rank-R1 bin.
__global__ __launch_bounds__(256) void k_hist(const float* __restrict__ conf,
                                              uint32_t* __restrict__ hsl,
                                              uint32_t* __restrict__ done1,
                                              uint32_t* __restrict__ hdr) {
    int f = blockIdx.x >> 3;
    int chunk = blockIdx.x & 7;
    __shared__ uint32_t h[NBINS]; // 16 KB
    __shared__ int is_last;
    for (int i = threadIdx.x; i < NBINS; i += 256) h[i] = 0;
    __syncthreads();
    const float4* c4 = (const float4*)(conf + (size_t)f * NPF + (size_t)chunk * (NPF / 8));
    for (int i = threadIdx.x; i < NPF / 32; i += 256) {
        float4 v = c4[i];
        atomicAdd(&h[conf_bin(v.x)], 1u);
        atomicAdd(&h[conf_bin(v.y)], 1u);
        atomicAdd(&h[conf_bin(v.z)], 1u);
        atomicAdd(&h[conf_bin(v.w)], 1u);
    }
    __syncthreads();
    uint32_t* slice = hsl + (size_t)blockIdx.x * NBINS;
    for (int i = threadIdx.x; i < NBINS; i += 256) slice[i] = h[i];
    __syncthreads();
    if (threadIdx.x == 0) {
        __threadfence();                       // release: slice stores visible
        uint32_t old = atomicAdd(&done1[f], 1u);
        is_last = (old == 7u);
        __threadfence();                       // acquire: other blocks' slices visible
    }
    __syncthreads();
    if (!is_last) return;

    // sum 8 slices into h
    const uint32_t* base = hsl + (size_t)(f * 8) * NBINS;
    for (int i = threadIdx.x; i < NBINS; i += 256) {
        uint32_t s = 0;
        #pragma unroll
        for (int k = 0; k < 8; k++) s += base[(size_t)k * NBINS + i];
        h[i] = s;
    }
    __syncthreads();
    // locate bin containing rank R1
    __shared__ uint32_t part[256];
    __shared__ uint32_t excl[256];
    __shared__ uint32_t hb[2]; // bin1, cb1
    const int b0 = threadIdx.x * (NBINS / 256);
    uint32_t s = 0;
    for (int j = 0; j < NBINS / 256; j++) s += h[b0 + j];
    part[threadIdx.x] = s;
    __syncthreads();
    if (threadIdx.x == 0) {
        uint32_t run = 0;
        for (int t = 0; t < 256; t++) { excl[t] = run; run += part[t]; }
    }
    __syncthreads();
    uint32_t e = excl[threadIdx.x];
    if (R1 >= e && R1 < e + part[threadIdx.x]) {
        uint32_t cum = e;
        for (int j = 0; j < NBINS / 256; j++) {
            uint32_t c2 = h[b0 + j];
            if (R1 < cum + c2) { hb[0] = (uint32_t)(b0 + j); hb[1] = cum; break; }
            cum += c2;
        }
    }
    __syncthreads();
    if (threadIdx.x < 2) hdr[f * 2 + threadIdx.x] = hb[threadIdx.x];
}

// K2: collect candidates in the rank bin (8 blocks/frame); last block rank-selects -> med[f]
__global__ __launch_bounds__(256) void k_collect(const float* __restrict__ conf,
                                                 const uint32_t* __restrict__ hdr,
                                                 uint32_t* __restrict__ ccnt,
                                                 float* __restrict__ cand,
                                                 uint32_t* __restrict__ done2,
                                                 float* __restrict__ med) {
    int f = blockIdx.x >> 3;
    int chunk = blockIdx.x & 7;
    int b1 = (int)hdr[f * 2];
    uint32_t cb1 = hdr[f * 2 + 1];
    float* buf = cand + (size_t)f * CAP;
    const float4* c4 = (const float4*)(conf + (size_t)f * NPF + (size_t)chunk * (NPF / 8));
    for (int i = threadIdx.x; i < NPF / 32; i += 256) {
        float4 q = c4[i];
        float vv[4] = {q.x, q.y, q.z, q.w};
        #pragma unroll
        for (int j = 0; j < 4; j++) {
            if (conf_bin(vv[j]) == b1) {
                uint32_t k = atomicAdd(&ccnt[f], 1u);
                if (k < CAP) buf[k] = vv[j];
            }
        }
    }
    __shared__ int is_last;
    __syncthreads();
    if (threadIdx.x == 0) {
        __threadfence();
        uint32_t old = atomicAdd(&done2[f], 1u);
        is_last = (old == 7u);
        __threadfence();
    }
    __syncthreads();
    if (!is_last) return;

    __shared__ float sc[CAP];
    __shared__ uint32_t m_sh;
    if (threadIdx.x == 0) m_sh = min(ccnt[f], (uint32_t)CAP);
    __syncthreads();
    int m = (int)m_sh;
    for (int i = threadIdx.x; i < m; i += 256) sc[i] = buf[i];
    __syncthreads();
    int target = (int)(R1 - cb1);
    for (int i = threadIdx.x; i < m; i += 256) {
        float v = sc[i];
        int r = 0;
        for (int j = 0; j < m; j++) {
            float w = sc[j];
            r += (w < v) || (w == v && j < i);
        }
        if (r == target) med[f] = v;   // exactly one match
    }
}

// K3: fused bbox (valid pts) + complexity sums; last block folds 2048 partials
__global__ __launch_bounds__(256) void k_stats(const float* __restrict__ pts,
                                               const float* __restrict__ conf,
                                               const float* __restrict__ med,
                                               float* __restrict__ pbf,
                                               double* __restrict__ pbd,
                                               uint32_t* __restrict__ pbc,
                                               uint32_t* __restrict__ done3,
                                               float* __restrict__ bbox,
                                               double* __restrict__ sums) {
    int f = blockIdx.x >> 5;
    int chunk = blockIdx.x & 31;
    const int GPB = NPF / 4 / 32; // 1152 float4-groups per block
    const size_t gbase = (size_t)f * (NPF / 4) + (size_t)chunk * GPB;
    const float4* c4 = (const float4*)conf + gbase;
    const float4* p4 = (const float4*)pts + gbase * 3;
    float q = med[f];
    float mnx = 1e30f, mny = 1e30f, mnz = 1e30f;
    float mxx = -1e30f, mxy = -1e30f, mxz = -1e30f;
    double s1 = 0.0, s2 = 0.0;
    uint32_t cnt = 0;
    for (int g = threadIdx.x; g < GPB; g += 256) {
        float4 cc = c4[g];
        float4 a = p4[3 * (size_t)g], b = p4[3 * (size_t)g + 1], d = p4[3 * (size_t)g + 2];
        float cv[4] = {cc.x, cc.y, cc.z, cc.w};
        float v[12] = {a.x, a.y, a.z, a.w, b.x, b.y, b.z, b.w, d.x, d.y, d.z, d.w};
        #pragma unroll
        for (int j = 0; j < 4; j++) {
            float c = cv[j];
            float x = v[3 * j], y = v[3 * j + 1], z = v[3 * j + 2];
            if (c > 0.1f) {
                float dd = sqrtf(x * x + y * y + z * z);
                s1 += (double)dd;
                s2 += (double)dd * (double)dd;
                cnt++;
                if (c >= q) {
                    mnx = fminf(mnx, x); mny = fminf(mny, y); mnz = fminf(mnz, z);
                    mxx = fmaxf(mxx, x); mxy = fmaxf(mxy, y); mxz = fmaxf(mxz, z);
                }
            }
        }
    }
    for (int o = 32; o > 0; o >>= 1) {
        mnx = fminf(mnx, __shfl_xor(mnx, o)); mny = fminf(mny, __shfl_xor(mny, o));
        mnz = fminf(mnz, __shfl_xor(mnz, o));
        mxx = fmaxf(mxx, __shfl_xor(mxx, o)); mxy = fmaxf(mxy, __shfl_xor(mxy, o));
        mxz = fmaxf(mxz, __shfl_xor(mxz, o));
        s1 += __shfl_xor(s1, o); s2 += __shfl_xor(s2, o);
        cnt += __shfl_xor(cnt, o);
    }
    __shared__ float  rf[6][4];
    __shared__ double rd[2][4];
    __shared__ uint32_t rc[4];
    __shared__ int is_last;
    int wave = threadIdx.x >> 6, lane = threadIdx.x & 63;
    if (lane == 0) {
        rf[0][wave] = mnx; rf[1][wave] = mny; rf[2][wave] = mnz;
        rf[3][wave] = mxx; rf[4][wave] = mxy; rf[5][wave] = mxz;
        rd[0][wave] = s1;  rd[1][wave] = s2;  rc[wave] = cnt;
    }
    __syncthreads();
    if (threadIdx.x == 0) {
        size_t b6 = (size_t)blockIdx.x * 6;
        pbf[b6 + 0] = fminf(fminf(rf[0][0], rf[0][1]), fminf(rf[0][2], rf[0][3]));
        pbf[b6 + 1] = fminf(fminf(rf[1][0], rf[1][1]), fminf(rf[1][2], rf[1][3]));
        pbf[b6 + 2] = fminf(fminf(rf[2][0], rf[2][1]), fminf(rf[2][2], rf[2][3]));
        pbf[b6 + 3] = fmaxf(fmaxf(rf[3][0], rf[3][1]), fmaxf(rf[3][2], rf[3][3]));
        pbf[b6 + 4] = fmaxf(fmaxf(rf[4][0], rf[4][1]), fmaxf(rf[4][2], rf[4][3]));
        pbf[b6 + 5] = fmaxf(fmaxf(rf[5][0], rf[5][1]), fmaxf(rf[5][2], rf[5][3]));
        pbd[(size_t)blockIdx.x * 2]     = rd[0][0] + rd[0][1] + rd[0][2] + rd[0][3];
        pbd[(size_t)blockIdx.x * 2 + 1] = rd[1][0] + rd[1][1] + rd[1][2] + rd[1][3];
        pbc[blockIdx.x] = rc[0] + rc[1] + rc[2] + rc[3];
        __threadfence();
        uint32_t old = atomicAdd(done3, 1u);
        is_last = (old == (uint32_t)(NBLK_STATS - 1));
        __threadfence();
    }
    __syncthreads();
    if (!is_last) return;

    // fold 2048 partials
    mnx = 1e30f; mny = 1e30f; mnz = 1e30f;
    mxx = -1e30f; mxy = -1e30f; mxz = -1e30f;
    s1 = 0.0; s2 = 0.0; cnt = 0;
    for (int b = threadIdx.x; b < NBLK_STATS; b += 256) {
        size_t b6 = (size_t)b * 6;
        mnx = fminf(mnx, pbf[b6 + 0]); mny = fminf(mny, pbf[b6 + 1]);
        mnz = fminf(mnz, pbf[b6 + 2]);
        mxx = fmaxf(mxx, pbf[b6 + 3]); mxy = fmaxf(mxy, pbf[b6 + 4]);
        mxz = fmaxf(mxz, pbf[b6 + 5]);
        s1 += pbd[(size_t)b * 2]; s2 += pbd[(size_t)b * 2 + 1];
        cnt += pbc[b];
    }
    for (int o = 32; o > 0; o >>= 1) {
        mnx = fminf(mnx, __shfl_xor(mnx, o)); mny = fminf(mny, __shfl_xor(mny, o));
        mnz = fminf(mnz, __shfl_xor(mnz, o));
        mxx = fmaxf(mxx, __shfl_xor(mxx, o)); mxy = fmaxf(mxy, __shfl_xor(mxy, o));
        mxz = fmaxf(mxz, __shfl_xor(mxz, o));
        s1 += __shfl_xor(s1, o); s2 += __shfl_xor(s2, o);
        cnt += __shfl_xor(cnt, o);
    }
    __syncthreads();
    if (lane == 0) {
        rf[0][wave] = mnx; rf[1][wave] = mny; rf[2][wave] = mnz;
        rf[3][wave] = mxx; rf[4][wave] = mxy; rf[5][wave] = mxz;
        rd[0][wave] = s1;  rd[1][wave] = s2;  rc[wave] = cnt;
    }
    __syncthreads();
    if (threadIdx.x == 0) {
        bbox[0] = fminf(fminf(rf[0][0], rf[0][1]), fminf(rf[0][2], rf[0][3]));
        bbox[1] = fminf(fminf(rf[1][0], rf[1][1]), fminf(rf[1][2], rf[1][3]));
        bbox[2] = fminf(fminf(rf[2][0], rf[2][1]), fminf(rf[2][2], rf[2][3]));
        bbox[3] = fmaxf(fmaxf(rf[3][0], rf[3][1]), fmaxf(rf[3][2], rf[3][3]));
        bbox[4] = fmaxf(fmaxf(rf[4][0], rf[4][1]), fmaxf(rf[4][2], rf[4][3]));
        bbox[5] = fmaxf(fmaxf(rf[5][0], rf[5][1]), fmaxf(rf[5][2], rf[5][3]));
        sums[0] = rd[0][0] + rd[0][1] + rd[0][2] + rd[0][3];
        sums[1] = rd[1][0] + rd[1][1] + rd[1][2] + rd[1][3];
        sums[2] = (double)(rc[0] + rc[1] + rc[2] + rc[3]);
    }
}

// K4: 3-scale LDS voxel bitmaps -> private slice (plain stores);
// last block per frame ORs 8 slices, popcounts, writes out (+complexity on f==0)
__global__ __launch_bounds__(256) void k_voxel(const float* __restrict__ pts,
                                               const float* __restrict__ conf,
                                               const float* __restrict__ med,
                                               const float* __restrict__ bbox,
                                               uint32_t* __restrict__ vsl,
                                               uint32_t* __restrict__ done4,
                                               const double* __restrict__ sums,
                                               float* __restrict__ out) {
    int f = blockIdx.x >> 3;
    int chunk = blockIdx.x & 7;
    __shared__ __align__(16) uint32_t bm[WORDS_BM];
    for (int i = threadIdx.x; i < WORDS_BM; i += 256) bm[i] = 0;
    float pmnx = bbox[0], pmny = bbox[1], pmnz = bbox[2];
    float ex = bbox[3] - pmnx, ey = bbox[4] - pmny, ez = bbox[5] - pmnz;
    float me = fminf(ex, fminf(ey, ez));
    float i40 = 40.0f / me, i20 = 20.0f / me, i10 = 10.0f / me;
    float q = med[f];
    __syncthreads();
    const size_t base = (size_t)f * NPF + (size_t)chunk * (NPF / 8);
    const float4* c4 = (const float4*)(conf + base);
    const float4* p4 = (const float4*)(pts + base * 3);
    for (int i = threadIdx.x; i < NPF / 32; i += 256) {
        float4 cc = c4[i];
        float4 a = p4[3 * (size_t)i], b = p4[3 * (size_t)i + 1], d = p4[3 * (size_t)i + 2];
        float cv[4] = {cc.x, cc.y, cc.z, cc.w};
        float v[12] = {a.x, a.y, a.z, a.w, b.x, b.y, b.z, b.w, d.x, d.y, d.z, d.w};
        #pragma unroll
        for (int j = 0; j < 4; j++) {
            float c = cv[j];
            if (c > 0.1f && c >= q) {
                float x = v[3 * j] - pmnx, y = v[3 * j + 1] - pmny, z = v[3 * j + 2] - pmnz;
                int cx, cy, cz, bit;
                cx = (int)floorf(x * i40); cy = (int)floorf(y * i40); cz = (int)floorf(z * i40);
                cx = min(max(cx, 0), 63); cy = min(max(cy, 0), 63); cz = min(max(cz, 0), 63);
                bit = (cx << 12) | (cy << 6) | cz;
                atomicOr(&bm[bit >> 5], 1u << (bit & 31));
                cx = (int)floorf(x * i20); cy = (int)floorf(y * i20); cz = (int)floorf(z * i20);
                cx = min(max(cx, 0), 31); cy = min(max(cy, 0), 31); cz = min(max(cz, 0), 31);
                bit = (cx << 10) | (cy << 5) | cz;
                atomicOr(&bm[8192 + (bit >> 5)], 1u << (bit & 31));
                cx = (int)floorf(x * i10); cy = (int)floorf(y * i10); cz = (int)floorf(z * i10);
                cx = min(max(cx, 0), 15); cy = min(max(cy, 0), 15); cz = min(max(cz, 0), 15);
                bit = (cx << 8) | (cy << 4) | cz;
                atomicOr(&bm[9216 + (bit >> 5)], 1u << (bit & 31));
            }
        }
    }
    __syncthreads();
    uint4* dst = (uint4*)(vsl + (size_t)blockIdx.x * WORDS_BM);
    const uint4* src = (const uint4*)bm;
    for (int i = threadIdx.x; i < WORDS_BM / 4; i += 256) dst[i] = src[i];
    __shared__ int is_last;
    __syncthreads();
    if (threadIdx.x == 0) {
        __threadfence();
        uint32_t old = atomicAdd(&done4[f], 1u);
        is_last = (old == 7u);
        __threadfence();
    }
    __syncthreads();
    if (!is_last) return;

    uint32_t c40 = 0, c20 = 0, c10 = 0;
    const uint32_t* fb = vsl + (size_t)(f * 8) * WORDS_BM;
    for (int i = threadIdx.x; i < WORDS_BM / 4; i += 256) {
        uint4 w = ((const uint4*)fb)[i];
        #pragma unroll
        for (int k = 1; k < 8; k++) {
            uint4 u = ((const uint4*)(fb + (size_t)k * WORDS_BM))[i];
            w.x |= u.x; w.y |= u.y; w.z |= u.z; w.w |= u.w;
        }
        uint32_t pc = __popc(w.x) + __popc(w.y) + __popc(w.z) + __popc(w.w);
        if (i < 2048) c40 += pc;
        else if (i < 2304) c20 += pc;
        else c10 += pc;
    }
    for (int o = 32; o > 0; o >>= 1) {
        c40 += __shfl_xor(c40, o);
        c20 += __shfl_xor(c20, o);
        c10 += __shfl_xor(c10, o);
    }
    __shared__ uint32_t red[3][4];
    int wave = threadIdx.x >> 6, lane = threadIdx.x & 63;
    if (lane == 0) { red[0][wave] = c40; red[1][wave] = c20; red[2][wave] = c10; }
    __syncthreads();
    if (threadIdx.x == 0) {
        uint32_t t40 = red[0][0] + red[0][1] + red[0][2] + red[0][3];
        uint32_t t20 = red[1][0] + red[1][1] + red[1][2] + red[1][3];
        uint32_t t10 = red[2][0] + red[2][1] + red[2][2] + red[2][3];
        out[0 * S_FRAMES + f] = (float)t10;
        out[1 * S_FRAMES + f] = (float)t20;
        out[2 * S_FRAMES + f] = (float)t40;
        out[3 * S_FRAMES + f] = (float)t20; // adaptive lambda == 20
        if (f == 0) {
            double n = sums[2];
            double mean = sums[0] / n;
            double var = (sums[1] - n * mean * mean) / (n - 1.0);
            out[4 * S_FRAMES] = (float)(sqrt(var) * (n / (double)TOT));
        }
    }
}

extern "C" void kernel_launch(void* const* d_in, const int* in_sizes, int n_in,
                              void* d_out, int out_size, void* d_ws, size_t ws_size,
                              hipStream_t stream) {
    const float* pts  = (const float*)d_in[0];
    const float* conf = (const float*)d_in[1];
    float* out = (float*)d_out;
    char* ws = (char*)d_ws;
    uint32_t* hsl   = (uint32_t*)(ws + OFF_SL);
    uint32_t* ctrs  = (uint32_t*)(ws + OFF_CTRS);
    uint32_t* done1 = ctrs;
    uint32_t* done2 = ctrs + 64;
    uint32_t* done3 = ctrs + 128;
    uint32_t* done4 = ctrs + 192;
    uint32_t* ccnt  = ctrs + 256;
    uint32_t* hdr   = (uint32_t*)(ws + OFF_HDR);
    float*    med   = (float*)(ws + OFF_MED);
    float*    bbox  = (float*)(ws + OFF_BBOX);
    double*   sums  = (double*)(ws + OFF_SUMS);
    float*    cand  = (float*)(ws + OFF_CAND);
    float*    pbf   = (float*)(ws + OFF_PBF);
    double*   pbd   = (double*)(ws + OFF_PBD);
    uint32_t* pbc   = (uint32_t*)(ws + OFF_PBC);
    uint32_t* vsl   = (uint32_t*)(ws + OFF_VSL);

    k_init   <<<1,            256, 0, stream>>>(ctrs);
    k_hist   <<<S_FRAMES * 8, 256, 0, stream>>>(conf, hsl, done1, hdr);
    k_collect<<<S_FRAMES * 8, 256, 0, stream>>>(conf, hdr, ccnt, cand, done2, med);
    k_stats  <<<NBLK_STATS,   256, 0, stream>>>(pts, conf, med, pbf, pbd, pbc, done3, bbox, sums);
    k_voxel  <<<S_FRAMES * 8, 256, 0, stream>>>(pts, conf, med, bbox, vsl, done4, sums, out);
}

// Round 6
// 108.717 us; speedup vs baseline: 2.7059x; 2.7059x over previous
//
#include <hip/hip_runtime.h>
#include <cstdint>

#define S_FRAMES 64
#define NPF      147456           // 384*384
#define TOT      (S_FRAMES * NPF) // 9437184
#define NBINS    4096
#define R1       73728u           // valid = c >= sorted[R1]  (== c >= median, exactly)
#define NBLK_STATS 2048
#define CAPC     512
#define WORDS_BM 9344             // 8192 (dim64,λ40) + 1024 (dim32,λ20) + 128 (dim16,λ10)

// ---- workspace layout (bytes) ----
#define OFF_MED  0                                  // 64 f32
#define OFF_BBOX 256                                // 6 f32
#define OFF_SUMS 320                                // 3 f64 (8-aligned)
#define OFF_PBF  384                                // 2048*6 f32
#define OFF_PBD  (OFF_PBF + NBLK_STATS * 6 * 4)     // 2048*2 f64
#define OFF_PBC  (OFF_PBD + NBLK_STATS * 2 * 8)     // 2048 u32
#define OFF_VSL  (OFF_PBC + NBLK_STATS * 4)         // voxel slices: 512 * 9344 * 4 = 19.1 MB (16-aligned)

__device__ __forceinline__ int conf_bin(float v) {
    int b = (int)(v * (float)NBINS);
    return b < 0 ? 0 : (b > NBINS - 1 ? NBINS - 1 : b);
}

// K1: per-frame exact rank-R1 order statistic, fully in-block.
// One block (1024 thr) per frame: LDS hist -> prefix scan -> candidate re-scan (L2-hot) -> rank select.
__global__ __launch_bounds__(1024) void k_median(const float* __restrict__ conf,
                                                 float* __restrict__ med) {
    int f = blockIdx.x;
    __shared__ uint32_t h[NBINS];       // 16 KB
    __shared__ uint32_t wsum[16], wexcl[16];
    __shared__ uint32_t binfo[2];       // bin1, cb1
    __shared__ float cbuf[CAPC];
    __shared__ uint32_t ccnt;
    const int tid = threadIdx.x;
    for (int i = tid; i < NBINS; i += 1024) h[i] = 0;
    if (tid == 0) ccnt = 0u;
    __syncthreads();

    const float4* c4 = (const float4*)(conf + (size_t)f * NPF);
    for (int i = tid; i < NPF / 4; i += 1024) {
        float4 v = c4[i];
        atomicAdd(&h[conf_bin(v.x)], 1u);
        atomicAdd(&h[conf_bin(v.y)], 1u);
        atomicAdd(&h[conf_bin(v.z)], 1u);
        atomicAdd(&h[conf_bin(v.w)], 1u);
    }
    __syncthreads();

    // each thread owns 4 bins; block-wide exclusive prefix of per-thread sums
    const int base = tid * 4;
    uint32_t s = h[base] + h[base + 1] + h[base + 2] + h[base + 3];
    const uint32_t lane = tid & 63, wave = tid >> 6;
    uint32_t scan = s;                   // inclusive scan within wave
    for (int o = 1; o < 64; o <<= 1) {
        uint32_t t = __shfl_up(scan, o);
        if (lane >= o) scan += t;
    }
    if (lane == 63) wsum[wave] = scan;
    __syncthreads();
    if (tid == 0) {
        uint32_t run = 0;
        for (int w = 0; w < 16; w++) { wexcl[w] = run; run += wsum[w]; }
    }
    __syncthreads();
    uint32_t excl = wexcl[wave] + (scan - s);
    if (R1 >= excl && R1 < excl + s) {
        uint32_t cum = excl;
        #pragma unroll
        for (int j = 0; j < 4; j++) {
            uint32_t c2 = h[base + j];
            if (R1 < cum + c2) { binfo[0] = (uint32_t)(base + j); binfo[1] = cum; break; }
            cum += c2;
        }
    }
    __syncthreads();
    const int b1 = (int)binfo[0];
    const uint32_t cb1 = binfo[1];

    // re-scan (L2-resident: 576 KB/frame) collecting candidates in the rank bin
    for (int i = tid; i < NPF / 4; i += 1024) {
        float4 v = c4[i];
        float vv[4] = {v.x, v.y, v.z, v.w};
        #pragma unroll
        for (int j = 0; j < 4; j++) {
            if (conf_bin(vv[j]) == b1) {
                uint32_t k = atomicAdd(&ccnt, 1u);
                if (k < CAPC) cbuf[k] = vv[j];
            }
        }
    }
    __syncthreads();
    const int m = (int)min(ccnt, (uint32_t)CAPC);
    const int target = (int)(R1 - cb1);
    for (int i = tid; i < m; i += 1024) {
        float v = cbuf[i];
        int r = 0;
        for (int j = 0; j < m; j++) {
            float w = cbuf[j];
            r += (w < v) || (w == v && j < i);
        }
        if (r == target) med[f] = v;  // exactly one thread matches
    }
}

// K2: fused bbox (valid pts) + complexity sums (mask pts), block partials. 32 blocks/frame.
__global__ __launch_bounds__(256) void k_stats(const float* __restrict__ pts,
                                               const float* __restrict__ conf,
                                               const float* __restrict__ med,
                                               float* __restrict__ pbf,
                                               double* __restrict__ pbd,
                                               uint32_t* __restrict__ pbc) {
    int f = blockIdx.x >> 5;
    int chunk = blockIdx.x & 31;
    const int GPB = NPF / 4 / 32; // 1152 float4-groups per block
    const size_t gbase = (size_t)f * (NPF / 4) + (size_t)chunk * GPB;
    const float4* c4 = (const float4*)conf + gbase;
    const float4* p4 = (const float4*)pts + gbase * 3;
    float q = med[f];
    float mnx = 1e30f, mny = 1e30f, mnz = 1e30f;
    float mxx = -1e30f, mxy = -1e30f, mxz = -1e30f;
    double s1 = 0.0, s2 = 0.0;
    uint32_t cnt = 0;
    for (int g = threadIdx.x; g < GPB; g += 256) {
        float4 cc = c4[g];
        float4 a = p4[3 * (size_t)g], b = p4[3 * (size_t)g + 1], d = p4[3 * (size_t)g + 2];
        float cv[4] = {cc.x, cc.y, cc.z, cc.w};
        float v[12] = {a.x, a.y, a.z, a.w, b.x, b.y, b.z, b.w, d.x, d.y, d.z, d.w};
        #pragma unroll
        for (int j = 0; j < 4; j++) {
            float c = cv[j];
            float x = v[3 * j], y = v[3 * j + 1], z = v[3 * j + 2];
            if (c > 0.1f) {
                float dd = sqrtf(x * x + y * y + z * z);
                s1 += (double)dd;
                s2 += (double)dd * (double)dd;
                cnt++;
                if (c >= q) {
                    mnx = fminf(mnx, x); mny = fminf(mny, y); mnz = fminf(mnz, z);
                    mxx = fmaxf(mxx, x); mxy = fmaxf(mxy, y); mxz = fmaxf(mxz, z);
                }
            }
        }
    }
    for (int o = 32; o > 0; o >>= 1) {
        mnx = fminf(mnx, __shfl_xor(mnx, o)); mny = fminf(mny, __shfl_xor(mny, o));
        mnz = fminf(mnz, __shfl_xor(mnz, o));
        mxx = fmaxf(mxx, __shfl_xor(mxx, o)); mxy = fmaxf(mxy, __shfl_xor(mxy, o));
        mxz = fmaxf(mxz, __shfl_xor(mxz, o));
        s1 += __shfl_xor(s1, o); s2 += __shfl_xor(s2, o);
        cnt += __shfl_xor(cnt, o);
    }
    __shared__ float  rf[6][4];
    __shared__ double rd[2][4];
    __shared__ uint32_t rc[4];
    int wave = threadIdx.x >> 6, lane = threadIdx.x & 63;
    if (lane == 0) {
        rf[0][wave] = mnx; rf[1][wave] = mny; rf[2][wave] = mnz;
        rf[3][wave] = mxx; rf[4][wave] = mxy; rf[5][wave] = mxz;
        rd[0][wave] = s1;  rd[1][wave] = s2;  rc[wave] = cnt;
    }
    __syncthreads();
    if (threadIdx.x == 0) {
        size_t b6 = (size_t)blockIdx.x * 6;
        pbf[b6 + 0] = fminf(fminf(rf[0][0], rf[0][1]), fminf(rf[0][2], rf[0][3]));
        pbf[b6 + 1] = fminf(fminf(rf[1][0], rf[1][1]), fminf(rf[1][2], rf[1][3]));
        pbf[b6 + 2] = fminf(fminf(rf[2][0], rf[2][1]), fminf(rf[2][2], rf[2][3]));
        pbf[b6 + 3] = fmaxf(fmaxf(rf[3][0], rf[3][1]), fmaxf(rf[3][2], rf[3][3]));
        pbf[b6 + 4] = fmaxf(fmaxf(rf[4][0], rf[4][1]), fmaxf(rf[4][2], rf[4][3]));
        pbf[b6 + 5] = fmaxf(fmaxf(rf[5][0], rf[5][1]), fmaxf(rf[5][2], rf[5][3]));
        pbd[(size_t)blockIdx.x * 2]     = rd[0][0] + rd[0][1] + rd[0][2] + rd[0][3];
        pbd[(size_t)blockIdx.x * 2 + 1] = rd[1][0] + rd[1][1] + rd[1][2] + rd[1][3];
        pbc[blockIdx.x] = rc[0] + rc[1] + rc[2] + rc[3];
    }
}

// K2b: fold 2048 block partials -> bbox + sums
__global__ __launch_bounds__(256) void k_reduce(const float* __restrict__ pbf,
                                                const double* __restrict__ pbd,
                                                const uint32_t* __restrict__ pbc,
                                                float* __restrict__ bbox,
                                                double* __restrict__ sums) {
    float mnx = 1e30f, mny = 1e30f, mnz = 1e30f;
    float mxx = -1e30f, mxy = -1e30f, mxz = -1e30f;
    double s1 = 0.0, s2 = 0.0;
    uint32_t cnt = 0;
    for (int b = threadIdx.x; b < NBLK_STATS; b += 256) {
        size_t b6 = (size_t)b * 6;
        mnx = fminf(mnx, pbf[b6 + 0]); mny = fminf(mny, pbf[b6 + 1]);
        mnz = fminf(mnz, pbf[b6 + 2]);
        mxx = fmaxf(mxx, pbf[b6 + 3]); mxy = fmaxf(mxy, pbf[b6 + 4]);
        mxz = fmaxf(mxz, pbf[b6 + 5]);
        s1 += pbd[(size_t)b * 2]; s2 += pbd[(size_t)b * 2 + 1];
        cnt += pbc[b];
    }
    for (int o = 32; o > 0; o >>= 1) {
        mnx = fminf(mnx, __shfl_xor(mnx, o)); mny = fminf(mny, __shfl_xor(mny, o));
        mnz = fminf(mnz, __shfl_xor(mnz, o));
        mxx = fmaxf(mxx, __shfl_xor(mxx, o)); mxy = fmaxf(mxy, __shfl_xor(mxy, o));
        mxz = fmaxf(mxz, __shfl_xor(mxz, o));
        s1 += __shfl_xor(s1, o); s2 += __shfl_xor(s2, o);
        cnt += __shfl_xor(cnt, o);
    }
    __shared__ float  rf[6][4];
    __shared__ double rd[2][4];
    __shared__ uint32_t rc[4];
    int wave = threadIdx.x >> 6, lane = threadIdx.x & 63;
    if (lane == 0) {
        rf[0][wave] = mnx; rf[1][wave] = mny; rf[2][wave] = mnz;
        rf[3][wave] = mxx; rf[4][wave] = mxy; rf[5][wave] = mxz;
        rd[0][wave] = s1;  rd[1][wave] = s2;  rc[wave] = cnt;
    }
    __syncthreads();
    if (threadIdx.x == 0) {
        bbox[0] = fminf(fminf(rf[0][0], rf[0][1]), fminf(rf[0][2], rf[0][3]));
        bbox[1] = fminf(fminf(rf[1][0], rf[1][1]), fminf(rf[1][2], rf[1][3]));
        bbox[2] = fminf(fminf(rf[2][0], rf[2][1]), fminf(rf[2][2], rf[2][3]));
        bbox[3] = fmaxf(fmaxf(rf[3][0], rf[3][1]), fmaxf(rf[3][2], rf[3][3]));
        bbox[4] = fmaxf(fmaxf(rf[4][0], rf[4][1]), fmaxf(rf[4][2], rf[4][3]));
        bbox[5] = fmaxf(fmaxf(rf[5][0], rf[5][1]), fmaxf(rf[5][2], rf[5][3]));
        sums[0] = rd[0][0] + rd[0][1] + rd[0][2] + rd[0][3];
        sums[1] = rd[1][0] + rd[1][1] + rd[1][2] + rd[1][3];
        sums[2] = (double)(rc[0] + rc[1] + rc[2] + rc[3]);
    }
}

// K3: 3-scale LDS voxel bitmaps -> private slice (plain stores, no atomics, no pre-zero)
__global__ __launch_bounds__(256) void k_voxel(const float* __restrict__ pts,
                                               const float* __restrict__ conf,
                                               const float* __restrict__ med,
                                               const float* __restrict__ bbox,
                                               uint32_t* __restrict__ vsl) {
    int f = blockIdx.x >> 3;
    int chunk = blockIdx.x & 7;
    __shared__ __align__(16) uint32_t bm[WORDS_BM];
    for (int i = threadIdx.x; i < WORDS_BM; i += 256) bm[i] = 0;
    float pmnx = bbox[0], pmny = bbox[1], pmnz = bbox[2];
    float ex = bbox[3] - pmnx, ey = bbox[4] - pmny, ez = bbox[5] - pmnz;
    float me = fminf(ex, fminf(ey, ez));
    float i40 = 40.0f / me, i20 = 20.0f / me, i10 = 10.0f / me;
    float q = med[f];
    __syncthreads();
    const size_t base = (size_t)f * NPF + (size_t)chunk * (NPF / 8);
    const float4* c4 = (const float4*)(conf + base);
    const float4* p4 = (const float4*)(pts + base * 3);
    for (int i = threadIdx.x; i < NPF / 32; i += 256) {
        float4 cc = c4[i];
        float4 a = p4[3 * (size_t)i], b = p4[3 * (size_t)i + 1], d = p4[3 * (size_t)i + 2];
        float cv[4] = {cc.x, cc.y, cc.z, cc.w};
        float v[12] = {a.x, a.y, a.z, a.w, b.x, b.y, b.z, b.w, d.x, d.y, d.z, d.w};
        #pragma unroll
        for (int j = 0; j < 4; j++) {
            float c = cv[j];
            if (c > 0.1f && c >= q) {
                float x = v[3 * j] - pmnx, y = v[3 * j + 1] - pmny, z = v[3 * j + 2] - pmnz;
                int cx, cy, cz, bit;
                cx = (int)floorf(x * i40); cy = (int)floorf(y * i40); cz = (int)floorf(z * i40);
                cx = min(max(cx, 0), 63); cy = min(max(cy, 0), 63); cz = min(max(cz, 0), 63);
                bit = (cx << 12) | (cy << 6) | cz;
                atomicOr(&bm[bit >> 5], 1u << (bit & 31));
                cx = (int)floorf(x * i20); cy = (int)floorf(y * i20); cz = (int)floorf(z * i20);
                cx = min(max(cx, 0), 31); cy = min(max(cy, 0), 31); cz = min(max(cz, 0), 31);
                bit = (cx << 10) | (cy << 5) | cz;
                atomicOr(&bm[8192 + (bit >> 5)], 1u << (bit & 31));
                cx = (int)floorf(x * i10); cy = (int)floorf(y * i10); cz = (int)floorf(z * i10);
                cx = min(max(cx, 0), 15); cy = min(max(cy, 0), 15); cz = min(max(cz, 0), 15);
                bit = (cx << 8) | (cy << 4) | cz;
                atomicOr(&bm[9216 + (bit >> 5)], 1u << (bit & 31));
            }
        }
    }
    __syncthreads();
    uint4* dst = (uint4*)(vsl + (size_t)blockIdx.x * WORDS_BM);
    const uint4* src = (const uint4*)bm;
    for (int i = threadIdx.x; i < WORDS_BM / 4; i += 256) dst[i] = src[i];
}

// K4: OR 8 slices per frame, popcount -> counts; f==0 also finalizes complexity
__global__ __launch_bounds__(256) void k_final(const uint32_t* __restrict__ vsl,
                                               const double* __restrict__ sums,
                                               float* __restrict__ out) {
    int f = blockIdx.x;
    uint32_t c40 = 0, c20 = 0, c10 = 0;
    const uint32_t* fb = vsl + (size_t)(f * 8) * WORDS_BM;
    for (int i = threadIdx.x; i < WORDS_BM / 4; i += 256) {
        uint4 w = ((const uint4*)fb)[i];
        #pragma unroll
        for (int k = 1; k < 8; k++) {
            uint4 u = ((const uint4*)(fb + (size_t)k * WORDS_BM))[i];
            w.x |= u.x; w.y |= u.y; w.z |= u.z; w.w |= u.w;
        }
        uint32_t pc = __popc(w.x) + __popc(w.y) + __popc(w.z) + __popc(w.w);
        if (i < 2048) c40 += pc;
        else if (i < 2304) c20 += pc;
        else c10 += pc;
    }
    for (int o = 32; o > 0; o >>= 1) {
        c40 += __shfl_xor(c40, o);
        c20 += __shfl_xor(c20, o);
        c10 += __shfl_xor(c10, o);
    }
    __shared__ uint32_t red[3][4];
    int wave = threadIdx.x >> 6, lane = threadIdx.x & 63;
    if (lane == 0) { red[0][wave] = c40; red[1][wave] = c20; red[2][wave] = c10; }
    __syncthreads();
    if (threadIdx.x == 0) {
        uint32_t t40 = red[0][0] + red[0][1] + red[0][2] + red[0][3];
        uint32_t t20 = red[1][0] + red[1][1] + red[1][2] + red[1][3];
        uint32_t t10 = red[2][0] + red[2][1] + red[2][2] + red[2][3];
        out[0 * S_FRAMES + f] = (float)t10;
        out[1 * S_FRAMES + f] = (float)t20;
        out[2 * S_FRAMES + f] = (float)t40;
        out[3 * S_FRAMES + f] = (float)t20; // adaptive lambda == 20
        if (f == 0) {
            double n = sums[2];
            double mean = sums[0] / n;
            double var = (sums[1] - n * mean * mean) / (n - 1.0);
            out[4 * S_FRAMES] = (float)(sqrt(var) * (n / (double)TOT));
        }
    }
}

extern "C" void kernel_launch(void* const* d_in, const int* in_sizes, int n_in,
                              void* d_out, int out_size, void* d_ws, size_t ws_size,
                              hipStream_t stream) {
    const float* pts  = (const float*)d_in[0];
    const float* conf = (const float*)d_in[1];
    float* out = (float*)d_out;
    char* ws = (char*)d_ws;
    float*    med  = (float*)(ws + OFF_MED);
    float*    bbox = (float*)(ws + OFF_BBOX);
    double*   sums = (double*)(ws + OFF_SUMS);
    float*    pbf  = (float*)(ws + OFF_PBF);
    double*   pbd  = (double*)(ws + OFF_PBD);
    uint32_t* pbc  = (uint32_t*)(ws + OFF_PBC);
    uint32_t* vsl  = (uint32_t*)(ws + OFF_VSL);

    k_median<<<S_FRAMES,     1024, 0, stream>>>(conf, med);
    k_stats <<<NBLK_STATS,    256, 0, stream>>>(pts, conf, med, pbf, pbd, pbc);
    k_reduce<<<1,             256, 0, stream>>>(pbf, pbd, pbc, bbox, sums);
    k_voxel <<<S_FRAMES * 8,  256, 0, stream>>>(pts, conf, med, bbox, vsl);
    k_final <<<S_FRAMES,      256, 0, stream>>>(vsl, sums, out);
}